// Round 16
// baseline (599.946 us; speedup 1.0000x reference)
//
#include <hip/hip_runtime.h>

#define BATCH 8
#define NPTS 4096
#define NSAMP 512   // npoint = NPTS/8

#define ROW_SHR(n) (0x110 | (n))
#define ROW_BCAST15 0x142
#define ROW_BCAST31 0x143

template <int CTRL, int RMASK>
__device__ __forceinline__ float fmax_dpp(float x) {
  int t = __builtin_amdgcn_update_dpp(0, __float_as_int(x), CTRL, RMASK, 0xf, true);
  return fmaxf(x, __int_as_float(t));
}

__device__ __forceinline__ float wave_max(float x) {
  x = fmax_dpp<ROW_SHR(1), 0xf>(x);
  x = fmax_dpp<ROW_SHR(2), 0xf>(x);
  x = fmax_dpp<ROW_SHR(4), 0xf>(x);
  x = fmax_dpp<ROW_SHR(8), 0xf>(x);
  x = fmax_dpp<ROW_BCAST15, 0xa>(x);
  x = fmax_dpp<ROW_BCAST31, 0xc>(x);
  return x;
}

// ---------------------------------------------------------------------------
// Weight prep.
// 16x16-scheme layers (scales 0/1 AND L22): transpose w[cin][cout] ->
// wt[cout][cinp] (cin padded to x4) for per-thread float4 VMEM loads.
// L20+L21 (fused wave scheme): wrow[wq][k][32] = {w20x[k], w20y[k], w20z[k],
// b20[k], w21[k][wq*24 .. +24), pad[4]} (k < 64) — contiguous s_load stream.
// ---------------------------------------------------------------------------
__device__ __forceinline__ void tsec(int g, const float* __restrict__ w,
                                     float* __restrict__ wt, int cin, int cinp,
                                     int cout, int base) {
  int local = g - base;
  if (local < 0 || local >= cinp * cout) return;
  int oc = local / cinp, ic = local % cinp;
  wt[base + local] = (ic < cin) ? w[ic * cout + oc] : 0.0f;
}

__device__ __forceinline__ void rowpack(int g, const float* __restrict__ w20,
                                        const float* __restrict__ b20,
                                        const float* __restrict__ w21,
                                        float* __restrict__ wt, int base) {
  int local = g - base;
  if (local < 0 || local >= 4 * 64 * 32) return;
  int wq = local / (64 * 32);
  int r = local % (64 * 32);
  int k = r / 32, j = r % 32;
  float v;
  if (j < 3) v = w20[j * 64 + k];
  else if (j == 3) v = b20[k];
  else if (j < 28) v = w21[k * 96 + wq * 24 + (j - 4)];
  else v = 0.0f;
  wt[base + local] = v;
}

#define W00 0
#define W01 128
#define W02 1152
#define W10 3200
#define W11 3456
#define W12 7552
#define WROW 15744
#define W22V 23936
#define WT_TOTAL 36224

__global__ __launch_bounds__(256) void prep_kernel(
    const float* w00, const float* w01, const float* w02,
    const float* w10, const float* w11, const float* w12,
    const float* w20, const float* b20, const float* w21, const float* w22,
    float* __restrict__ wt) {
  int g = blockIdx.x * 256 + threadIdx.x;
  tsec(g, w00, wt, 3, 4, 32, W00);
  tsec(g, w01, wt, 32, 32, 32, W01);
  tsec(g, w02, wt, 32, 32, 64, W02);
  tsec(g, w10, wt, 3, 4, 64, W10);
  tsec(g, w11, wt, 64, 64, 64, W11);
  tsec(g, w12, wt, 64, 64, 128, W12);
  rowpack(g, w20, b20, w21, wt, WROW);
  tsec(g, w22, wt, 96, 96, 128, W22V);   // L22 vector-weight transpose
}

// ---------------------------------------------------------------------------
// 16x16-scheme MLP building blocks (16 n-threads x 16 oc-threads).
// Input-channel order is sequential 0..CIN-1 => bitwise identical to ref.
// ---------------------------------------------------------------------------
template <int TOC, int TN>
__device__ __forceinline__ void ib(float (&acc)[TOC][TN], const float* bias) {
#pragma unroll
  for (int j = 0; j < TOC; ++j) {
    float bj = bias[j];
#pragma unroll
    for (int i = 0; i < TN; ++i) acc[j][i] = bj;
  }
}

template <int CIN4, int TOC, int TN, int NTPI, int WS>
__device__ __forceinline__ void layer_acc(const float* __restrict__ wtb,
                                          const float* hin,
                                          float (&acc)[TOC][TN], int tn) {
#pragma unroll 2
  for (int c4 = 0; c4 < CIN4; ++c4) {
    float hv[4][TN];
#pragma unroll
    for (int k = 0; k < 4; ++k) {
      const float* src = &hin[(c4 * 4 + k) * NTPI + tn * TN];
      if constexpr (TN == 1) {
        hv[k][0] = src[0];
      } else if constexpr (TN == 2) {
        float2 v = *(const float2*)src; hv[k][0] = v.x; hv[k][1] = v.y;
      } else {
        float4 v = *(const float4*)src;
        hv[k][0] = v.x; hv[k][1] = v.y; hv[k][2] = v.z; hv[k][3] = v.w;
      }
    }
#pragma unroll
    for (int j = 0; j < TOC; ++j) {
      float4 w4 = *(const float4*)&wtb[j * WS + c4 * 4];
#pragma unroll
      for (int i = 0; i < TN; ++i) {
        acc[j][i] = fmaf(hv[0][i], w4.x, acc[j][i]);
        acc[j][i] = fmaf(hv[1][i], w4.y, acc[j][i]);
        acc[j][i] = fmaf(hv[2][i], w4.z, acc[j][i]);
        acc[j][i] = fmaf(hv[3][i], w4.w, acc[j][i]);
      }
    }
  }
}

template <int TOC, int TN, int NTPO>
__device__ __forceinline__ void store_relu(float* hout,
                                           float (&acc)[TOC][TN], int tn) {
#pragma unroll
  for (int j = 0; j < TOC; ++j) {
    float* dst = &hout[j * NTPO + tn * TN];
    if constexpr (TN == 1) {
      dst[0] = fmaxf(acc[j][0], 0.0f);
    } else if constexpr (TN == 2) {
      *(float2*)dst = make_float2(fmaxf(acc[j][0], 0.0f),
                                  fmaxf(acc[j][1], 0.0f));
    } else {
      *(float4*)dst = make_float4(fmaxf(acc[j][0], 0.0f),
                                  fmaxf(acc[j][1], 0.0f),
                                  fmaxf(acc[j][2], 0.0f),
                                  fmaxf(acc[j][3], 0.0f));
    }
  }
}

template <int TOC, int TN>
__device__ __forceinline__ void rmax_upd(float (&r)[TOC],
                                         float (&acc)[TOC][TN]) {
#pragma unroll
  for (int j = 0; j < TOC; ++j) {
    float m = 0.0f;   // relu floor
#pragma unroll
    for (int i = 0; i < TN; ++i) m = fmaxf(m, acc[j][i]);
    r[j] = fmaxf(r[j], m);
  }
}

// max over n-tile (relu floor), reduce over the 16 tn lanes, tn==0 lanes
// accumulate v*wf into the caller's dot register.
template <int TOC, int TN>
__device__ __forceinline__ float rmax_dot(const float* wfp,
                                          float (&acc)[TOC][TN], int tn) {
  float s = 0.0f;
#pragma unroll
  for (int j = 0; j < TOC; ++j) {
    float v = 0.0f;
#pragma unroll
    for (int i = 0; i < TN; ++i) v = fmaxf(v, acc[j][i]);
    v = fmaxf(v, __shfl_xor(v, 1));
    v = fmaxf(v, __shfl_xor(v, 2));
    v = fmaxf(v, __shfl_xor(v, 4));
    v = fmaxf(v, __shfl_xor(v, 8));
    if (tn == 0) s = fmaf(v, wfp[j], s);
  }
  return s;
}

// ---------------------------------------------------------------------------
// Fused pipelined kernel (producer FPS blocks + per-sample consumers).
// LDS = 6160 floats = 24640 B -> 6 blocks/CU.
//   head @ 0..15: ticket@0, bc@4, wsum@8
//   h2   @ 16    [96][64]
//   transient aliases inside h2 region (dead before W6):
//     masks u64[3][64] @16..400 | gl u16[176] @400..488 |
//     cbuf[4][68] @488..760 | sB @760..2936 | sA @2936..5112
// L21: fused wave scheme (scalar 8KB/wq stream, L20 recomputed on the fly).
// L22: 16x16 scheme with float4 VMEM weights (L1-cached, prefetchable).
// ---------------------------------------------------------------------------
__global__ __launch_bounds__(256) void fused_kernel(
    const float* __restrict__ pcd, float* __restrict__ new_xyz,
    int* __restrict__ ctrl, const float* __restrict__ wt,
    const float* __restrict__ b00, const float* __restrict__ b01,
    const float* __restrict__ b02, const float* __restrict__ b10,
    const float* __restrict__ b11, const float* __restrict__ b12,
    const float* __restrict__ b21, const float* __restrict__ b22,
    const float* __restrict__ wf, const float* __restrict__ bf,
    float* __restrict__ out) {
  __shared__ __align__(16) float lds[6160];   // 24640 B

  const int tid = threadIdx.x;
  int* progress = ctrl + 8;

  if (tid == 0) ((int*)lds)[0] = atomicAdd(&ctrl[0], 1);
  __syncthreads();
  const int ticket = ((int*)lds)[0];

  if (ticket < BATCH) {
    // ================= producer: FPS for batch = ticket =================
    const int b = ticket;
    const int t = tid;
    const int wave = t >> 6, lane = t & 63;
    const float* xb = pcd + (size_t)b * NPTS * 3;
    float4* slot = (float4*)(lds + 16);        // [2][4] parity dbuf

    float X[16], Y[16], Z[16], mind[16];
    {
      float f[48];
      float4* vv = (float4*)f;
      const float4* src = (const float4*)xb + t * 12;
#pragma unroll
      for (int q = 0; q < 12; ++q) vv[q] = src[q];
#pragma unroll
      for (int j = 0; j < 16; ++j) {
        X[j] = f[3 * j + 0]; Y[j] = f[3 * j + 1]; Z[j] = f[3 * j + 2];
        mind[j] = 10000000000.0f;
      }
    }
    float px = xb[0], py = xb[1], pz = xb[2];

    for (int it = 0; it < NSAMP; ++it) {
      if (t == 0) {
        int* dst = (int*)(new_xyz + ((size_t)b * NSAMP + it) * 3);
        atomicExch(&dst[0], __float_as_int(px));
        atomicExch(&dst[1], __float_as_int(py));
        atomicExch(&dst[2], __float_as_int(pz));
        if ((it & 7) == 7)
          __hip_atomic_store(&progress[b], it + 1, __ATOMIC_RELEASE,
                             __HIP_MEMORY_SCOPE_AGENT);
      }
      float bv = -1.0f, bx = 0.0f, by = 0.0f, bz = 0.0f;
#pragma unroll
      for (int j = 0; j < 16; ++j) {
        float dx = __fsub_rn(X[j], px);
        float dy = __fsub_rn(Y[j], py);
        float dz = __fsub_rn(Z[j], pz);
        float d = __fadd_rn(__fadd_rn(__fmul_rn(dx, dx), __fmul_rn(dy, dy)),
                            __fmul_rn(dz, dz));
        float m = fminf(mind[j], d);
        mind[j] = m;
        bool g = m > bv;
        bv = g ? m : bv;
        bx = g ? X[j] : bx; by = g ? Y[j] : by; bz = g ? Z[j] : bz;
      }
      float wmax = __int_as_float(
          __builtin_amdgcn_readlane(__float_as_int(wave_max(bv)), 63));
      unsigned long long msk = __ballot(bv == wmax);
      if (lane == __ffsll(msk) - 1)
        slot[(it & 1) * 4 + wave] = make_float4(bx, by, bz, wmax);
      __syncthreads();
      float4 cur = slot[(it & 1) * 4 + 0];
#pragma unroll
      for (int w = 1; w < 4; ++w) {
        float4 sw = slot[(it & 1) * 4 + w];
        if (sw.w > cur.w) cur = sw;
      }
      px = cur.x; py = cur.y; pz = cur.z;
    }
    return;
  }

  // ================= consumer: ball query + MLPs for one sample =========
  const int tk = ticket - BATCH;
  const int b = tk & 7;
  const int s = tk >> 3;
  const int bs = (b << 9) | s;
  const int lane = tid & 63;
  const int wave = tid >> 6;
  const int tn = tid & 15, toc = tid >> 4;
  const float* xb = pcd + (size_t)b * NPTS * 3;

  float* bc = lds + 4;
  float* wsum = lds + 8;
  float* h2 = lds + 16;                                   // [96][64]
  unsigned long long* masks = (unsigned long long*)(lds + 16);   // 16..400
  unsigned short* gl = (unsigned short*)(lds + 400);      // 400..488
  float* cbuf = lds + 488;                                // 488..760
  float* sB = lds + 760;                                  // 760..2936
  float* sA = lds + 2936;                                 // 2936..5112

  if (tid == 0) {
    while (__hip_atomic_load(&progress[b], __ATOMIC_ACQUIRE,
                             __HIP_MEMORY_SCOPE_AGENT) <= s)
      __builtin_amdgcn_s_sleep(2);
    const int* src = (const int*)(new_xyz + (size_t)bs * 3);
    bc[0] = __int_as_float(__hip_atomic_load(&src[0], __ATOMIC_RELAXED,
                                             __HIP_MEMORY_SCOPE_AGENT));
    bc[1] = __int_as_float(__hip_atomic_load(&src[1], __ATOMIC_RELAXED,
                                             __HIP_MEMORY_SCOPE_AGENT));
    bc[2] = __int_as_float(__hip_atomic_load(&src[2], __ATOMIC_RELAXED,
                                             __HIP_MEMORY_SCOPE_AGENT));
  }
  __syncthreads();
  const float cx = bc[0], cy = bc[1], cz = bc[2];

  // ---- P1: in-radius bitmasks (3 radii x 64 chunks) ----
  const float r2a = (float)(0.1 * 0.1);
  const float r2b = (float)(0.2 * 0.2);
  const float r2c = (float)(0.4 * 0.4);
#pragma unroll 4
  for (int j = 0; j < 16; ++j) {
    int i = (j << 8) | tid;
    const float* p = xb + i * 3;
    float dx = __fsub_rn(cx, p[0]);
    float dy = __fsub_rn(cy, p[1]);
    float dz = __fsub_rn(cz, p[2]);
    float sq = __fadd_rn(__fadd_rn(__fmul_rn(dx, dx), __fmul_rn(dy, dy)),
                         __fmul_rn(dz, dz));
    unsigned long long m0 = __ballot(sq < r2a);
    unsigned long long m1 = __ballot(sq < r2b);
    unsigned long long m2 = __ballot(sq < r2c);
    if (lane == 0) {
      int c = (j << 2) | wave;
      masks[0 * 64 + c] = m0; masks[1 * 64 + c] = m1; masks[2 * 64 + c] = m2;
    }
  }
  __syncthreads();

  // ---- P2: wave s builds ordered padded list for scale s ----
  if (wave < 3) {
    const int ns  = (wave == 0) ? 16 : (wave == 1) ? 32 : 128;
    const int off = (wave == 0) ? 0  : (wave == 1) ? 16 : 48;
    unsigned long long m = masks[wave * 64 + lane];
    int pc = (int)__popcll(m);
    int incl = pc;
#pragma unroll
    for (int o = 1; o < 64; o <<= 1) {
      int u = __shfl_up(incl, o);
      if (lane >= o) incl += u;
    }
    int ex = incl - pc;
    int total = __shfl(incl, 63);
    unsigned short* glw = gl + off;
    unsigned long long mm = m;
    int p = ex;
    while (mm && p < ns) {
      int l = (int)__builtin_ctzll(mm);
      mm &= mm - 1;
      glw[p++] = (unsigned short)((lane << 6) | l);
    }
    int cnt = total < ns ? total : ns;
    unsigned long long nz = __ballot(pc > 0);
    int fl = __ffsll(nz) - 1;
    int myf = (lane << 6) | (int)__builtin_ctzll(m | 0x8000000000000000ull);
    int fidx = __shfl(myf, fl);
    for (int k = cnt + lane; k < ns; k += 64) glw[k] = (unsigned short)fidx;
  }
  __syncthreads();

  // W0: pad row + stage c0 (0-15) and c1 (16-47); scale-2 coords -> regs
  const int gi0 = gl[48 + lane];
  const int gi1 = gl[112 + lane];
  if (tid < 68) cbuf[3 * 68 + tid] = 0.0f;
  if (tid < 48) {
    int j = gl[tid];
    const float* p = xb + 3 * j;
    cbuf[0 * 68 + tid] = __fsub_rn(p[0], cx);
    cbuf[1 * 68 + tid] = __fsub_rn(p[1], cy);
    cbuf[2 * 68 + tid] = __fsub_rn(p[2], cz);
  }
  const float* q0 = xb + 3 * gi0;
  const float* q1 = xb + 3 * gi1;
  const float dx0 = __fsub_rn(q0[0], cx);
  const float dy0 = __fsub_rn(q0[1], cy);
  const float dz0 = __fsub_rn(q0[2], cz);
  const float dx1 = __fsub_rn(q1[0], cx);
  const float dy1 = __fsub_rn(q1[1], cy);
  const float dz1 = __fsub_rn(q1[2], cz);
  __syncthreads();

  const int wq = __builtin_amdgcn_readfirstlane(wave);
  float dot = 0.0f;

  // W1: L00  cbuf -> sB (stride 18)
  {
    float a[2][1]; ib<2, 1>(a, b00 + toc * 2);
    layer_acc<1, 2, 1, 68, 4>(wt + W00 + (toc * 2) * 4, cbuf, a, tn);
    store_relu<2, 1, 18>(sB + (toc * 2) * 18, a, tn);
  }
  __syncthreads();

  // W2: L01  sB -> sA (stride 18)
  {
    float a[2][1]; ib<2, 1>(a, b01 + toc * 2);
    layer_acc<8, 2, 1, 18, 32>(wt + W01 + (toc * 2) * 32, sB, a, tn);
    store_relu<2, 1, 18>(sA + (toc * 2) * 18, a, tn);
  }
  __syncthreads();

  // W3: L02 sA -> dot  ||  L10 cbuf+16 -> sB (stride 34)
  {
    float a[4][1]; ib<4, 1>(a, b02 + toc * 4);
    layer_acc<8, 4, 1, 18, 32>(wt + W02 + (toc * 4) * 32, sA, a, tn);
    dot += rmax_dot<4, 1>(wf + toc * 4, a, tn);
    float a1[4][2]; ib<4, 2>(a1, b10 + toc * 4);
    layer_acc<1, 4, 2, 68, 4>(wt + W10 + (toc * 4) * 4, cbuf + 16, a1, tn);
    store_relu<4, 2, 34>(sB + (toc * 4) * 34, a1, tn);
  }
  __syncthreads();

  // W4: L11 sB -> sA (stride 34)
  {
    float a[4][2]; ib<4, 2>(a, b11 + toc * 4);
    layer_acc<16, 4, 2, 34, 64>(wt + W11 + (toc * 4) * 64, sB, a, tn);
    store_relu<4, 2, 34>(sA + (toc * 4) * 34, a, tn);
  }
  __syncthreads();

  // W5: L12 sA -> dot (scale 1 done; sA/sB/cbuf die here)
  {
    float a[8][2]; ib<8, 2>(a, b12 + toc * 8);
    layer_acc<16, 8, 2, 34, 64>(wt + W12 + (toc * 8) * 64, sA, a, tn);
    dot += rmax_dot<8, 2>(wf + 64 + toc * 8, a, tn);
  }
  __syncthreads();

  float rm2[8];
#pragma unroll
  for (int j = 0; j < 8; ++j) rm2[j] = 0.0f;

  // W6: fused L20+L21 (t0) -> h2 (wave scheme, scalar weight stream)
  {
    const float* wp = wt + WROW + wq * 2048;   // [k][32]
    const float* bp = b21 + wq * 24;
    float acc[24];
#pragma unroll
    for (int j = 0; j < 24; ++j) acc[j] = bp[j];
#pragma unroll 4
    for (int k = 0; k < 64; ++k) {
      const float* row = wp + k * 32;
      float a2 = row[3];
      a2 = fmaf(dx0, row[0], a2);
      a2 = fmaf(dy0, row[1], a2);
      a2 = fmaf(dz0, row[2], a2);
      float hv = fmaxf(a2, 0.0f);
#pragma unroll
      for (int j = 0; j < 24; ++j) acc[j] = fmaf(hv, row[4 + j], acc[j]);
    }
#pragma unroll
    for (int j = 0; j < 24; ++j)
      h2[(wq * 24 + j) * 64 + lane] = fmaxf(acc[j], 0.0f);
  }
  __syncthreads();

  // W7: L22(t0) 16x16 scheme, float4 VMEM weights -> rm2
  {
    float a[8][4]; ib<8, 4>(a, b22 + toc * 8);
    layer_acc<24, 8, 4, 64, 96>(wt + W22V + (toc * 8) * 96, h2, a, tn);
    rmax_upd<8, 4>(rm2, a);
  }
  __syncthreads();

  // W8: fused L20+L21 (t1) -> h2
  {
    const float* wp = wt + WROW + wq * 2048;
    const float* bp = b21 + wq * 24;
    float acc[24];
#pragma unroll
    for (int j = 0; j < 24; ++j) acc[j] = bp[j];
#pragma unroll 4
    for (int k = 0; k < 64; ++k) {
      const float* row = wp + k * 32;
      float a2 = row[3];
      a2 = fmaf(dx1, row[0], a2);
      a2 = fmaf(dy1, row[1], a2);
      a2 = fmaf(dz1, row[2], a2);
      float hv = fmaxf(a2, 0.0f);
#pragma unroll
      for (int j = 0; j < 24; ++j) acc[j] = fmaf(hv, row[4 + j], acc[j]);
    }
#pragma unroll
    for (int j = 0; j < 24; ++j)
      h2[(wq * 24 + j) * 64 + lane] = fmaxf(acc[j], 0.0f);
  }
  __syncthreads();

  // W9: L22(t1) 16x16 -> rm2; 16-lane reduce; tn==0 accumulates dot
  {
    float a[8][4]; ib<8, 4>(a, b22 + toc * 8);
    layer_acc<24, 8, 4, 64, 96>(wt + W22V + (toc * 8) * 96, h2, a, tn);
    rmax_upd<8, 4>(rm2, a);
#pragma unroll
    for (int j = 0; j < 8; ++j) {
      float v = rm2[j];
      v = fmaxf(v, __shfl_xor(v, 1));
      v = fmaxf(v, __shfl_xor(v, 2));
      v = fmaxf(v, __shfl_xor(v, 4));
      v = fmaxf(v, __shfl_xor(v, 8));
      if (tn == 0) dot = fmaf(v, wf[192 + toc * 8 + j], dot);
    }
  }

  // W10: block sum of per-thread partial dots
#pragma unroll
  for (int o = 1; o < 64; o <<= 1) dot += __shfl_xor(dot, o);
  if (lane == 0) wsum[wq] = dot;
  __syncthreads();
  if (tid == 0)
    out[bs] = wsum[0] + wsum[1] + wsum[2] + wsum[3] + bf[0];
}

extern "C" void kernel_launch(void* const* d_in, const int* in_sizes, int n_in,
                              void* d_out, int out_size, void* d_ws, size_t ws_size,
                              hipStream_t stream) {
  const float* pcd = (const float*)d_in[0];
  float* wsf = (float*)d_ws;
  float* new_xyz = wsf;                 // 12288 floats
  float* wt = wsf + 12288;              // 36224 floats
  int* ctrl = (int*)(wsf + 48512);      // [0]=claim, [8..15]=progress

  hipMemsetAsync(ctrl, 0, 64, stream);

  prep_kernel<<<(WT_TOTAL + 255) / 256, 256, 0, stream>>>(
      (const float*)d_in[1], (const float*)d_in[3], (const float*)d_in[5],
      (const float*)d_in[7], (const float*)d_in[9], (const float*)d_in[11],
      (const float*)d_in[13], (const float*)d_in[14], (const float*)d_in[15],
      (const float*)d_in[17], wt);

  fused_kernel<<<BATCH * NSAMP + BATCH, 256, 0, stream>>>(
      pcd, new_xyz, ctrl, wt,
      (const float*)d_in[2],  (const float*)d_in[4],  (const float*)d_in[6],
      (const float*)d_in[8],  (const float*)d_in[10], (const float*)d_in[12],
      (const float*)d_in[16], (const float*)d_in[18],
      (const float*)d_in[19], (const float*)d_in[20],
      (float*)d_out);
}

// Round 17
// 481.842 us; speedup vs baseline: 1.2451x; 1.2451x over previous
//
#include <hip/hip_runtime.h>

#define BATCH 8
#define NPTS 4096
#define NSAMP 512   // npoint = NPTS/8

#define ROW_SHR(n) (0x110 | (n))
#define ROW_BCAST15 0x142
#define ROW_BCAST31 0x143

typedef __attribute__((ext_vector_type(8))) short bf16x8;
typedef __attribute__((ext_vector_type(4))) float f32x4;

__device__ __forceinline__ unsigned short f2bf(float f) {
  unsigned u = __float_as_uint(f);
  unsigned r = (u + 0x7FFFu + ((u >> 16) & 1u)) >> 16;
  return (unsigned short)r;
}
__device__ __forceinline__ float bf2f(unsigned short h) {
  return __uint_as_float(((unsigned)h) << 16);
}

template <int CTRL, int RMASK>
__device__ __forceinline__ float fmax_dpp(float x) {
  int t = __builtin_amdgcn_update_dpp(0, __float_as_int(x), CTRL, RMASK, 0xf, true);
  return fmaxf(x, __int_as_float(t));
}

__device__ __forceinline__ float wave_max(float x) {
  x = fmax_dpp<ROW_SHR(1), 0xf>(x);
  x = fmax_dpp<ROW_SHR(2), 0xf>(x);
  x = fmax_dpp<ROW_SHR(4), 0xf>(x);
  x = fmax_dpp<ROW_SHR(8), 0xf>(x);
  x = fmax_dpp<ROW_BCAST15, 0xa>(x);
  x = fmax_dpp<ROW_BCAST31, 0xc>(x);
  return x;
}

// ---------------------------------------------------------------------------
// Weight prep.
// Scales 0/1: transpose w[cin][cout] -> wt[cout][cinp] (float4 loads).
// L20+L21 fused wave scheme: wrow[wq][k][32] = {w20xyz[k], b20[k],
//   w21[k][wq*24..+24), pad} (k<64) — contiguous s_load stream.
// L22: dual-bf16 MFMA A-fragments. For tile (ot 0..7, ks 0..2), lane l:
//   oc = ot*16 + (l&15), k = ks*32 + (l>>4)*8 + e  (e 0..7)
//   aw[(ot*3+ks)*64 + l][0..7] = hi bf16, [8..15] = lo bf16.
// ---------------------------------------------------------------------------
__device__ __forceinline__ void tsec(int g, const float* __restrict__ w,
                                     float* __restrict__ wt, int cin, int cinp,
                                     int cout, int base) {
  int local = g - base;
  if (local < 0 || local >= cinp * cout) return;
  int oc = local / cinp, ic = local % cinp;
  wt[base + local] = (ic < cin) ? w[ic * cout + oc] : 0.0f;
}

__device__ __forceinline__ void rowpack(int g, const float* __restrict__ w20,
                                        const float* __restrict__ b20,
                                        const float* __restrict__ w21,
                                        float* __restrict__ wt, int base) {
  int local = g - base;
  if (local < 0 || local >= 4 * 64 * 32) return;
  int wq = local / (64 * 32);
  int r = local % (64 * 32);
  int k = r / 32, j = r % 32;
  float v;
  if (j < 3) v = w20[j * 64 + k];
  else if (j == 3) v = b20[k];
  else if (j < 28) v = w21[k * 96 + wq * 24 + (j - 4)];
  else v = 0.0f;
  wt[base + local] = v;
}

__device__ __forceinline__ void awfill(int g, const float* __restrict__ w22,
                                       unsigned short* __restrict__ aw,
                                       int base) {
  int id = g - base;
  if (id < 0 || id >= 12288) return;
  int e = id & 7;
  int l = (id >> 3) & 63;
  int bq = id >> 9;                    // 0..23 = ot*3 + ks
  int ot = bq / 3, ks = bq % 3;
  int oc = ot * 16 + (l & 15);
  int k = ks * 32 + (l >> 4) * 8 + e;
  float v = w22[k * 128 + oc];
  unsigned short h = f2bf(v);
  unsigned short lo = f2bf(__fsub_rn(v, bf2f(h)));
  aw[(bq * 64 + l) * 16 + e] = h;
  aw[(bq * 64 + l) * 16 + 8 + e] = lo;
}

#define W00 0
#define W01 128
#define W02 1152
#define W10 3200
#define W11 3456
#define W12 7552
#define WROW 15744
#define AWID 23936
#define ID_TOTAL 36224

__global__ __launch_bounds__(256) void prep_kernel(
    const float* w00, const float* w01, const float* w02,
    const float* w10, const float* w11, const float* w12,
    const float* w20, const float* b20, const float* w21, const float* w22,
    float* __restrict__ wt, unsigned short* __restrict__ aw) {
  int g = blockIdx.x * 256 + threadIdx.x;
  tsec(g, w00, wt, 3, 4, 32, W00);
  tsec(g, w01, wt, 32, 32, 32, W01);
  tsec(g, w02, wt, 32, 32, 64, W02);
  tsec(g, w10, wt, 3, 4, 64, W10);
  tsec(g, w11, wt, 64, 64, 64, W11);
  tsec(g, w12, wt, 64, 64, 128, W12);
  rowpack(g, w20, b20, w21, wt, WROW);
  awfill(g, w22, aw, AWID);
}

// ---------------------------------------------------------------------------
// 16x16-scheme MLP building blocks (16 n-threads x 16 oc-threads).
// ---------------------------------------------------------------------------
template <int TOC, int TN>
__device__ __forceinline__ void ib(float (&acc)[TOC][TN], const float* bias) {
#pragma unroll
  for (int j = 0; j < TOC; ++j) {
    float bj = bias[j];
#pragma unroll
    for (int i = 0; i < TN; ++i) acc[j][i] = bj;
  }
}

template <int CIN4, int TOC, int TN, int NTPI, int WS>
__device__ __forceinline__ void layer_acc(const float* __restrict__ wtb,
                                          const float* hin,
                                          float (&acc)[TOC][TN], int tn) {
#pragma unroll 2
  for (int c4 = 0; c4 < CIN4; ++c4) {
    float hv[4][TN];
#pragma unroll
    for (int k = 0; k < 4; ++k) {
      const float* src = &hin[(c4 * 4 + k) * NTPI + tn * TN];
      if constexpr (TN == 1) {
        hv[k][0] = src[0];
      } else if constexpr (TN == 2) {
        float2 v = *(const float2*)src; hv[k][0] = v.x; hv[k][1] = v.y;
      } else {
        float4 v = *(const float4*)src;
        hv[k][0] = v.x; hv[k][1] = v.y; hv[k][2] = v.z; hv[k][3] = v.w;
      }
    }
#pragma unroll
    for (int j = 0; j < TOC; ++j) {
      float4 w4 = *(const float4*)&wtb[j * WS + c4 * 4];
#pragma unroll
      for (int i = 0; i < TN; ++i) {
        acc[j][i] = fmaf(hv[0][i], w4.x, acc[j][i]);
        acc[j][i] = fmaf(hv[1][i], w4.y, acc[j][i]);
        acc[j][i] = fmaf(hv[2][i], w4.z, acc[j][i]);
        acc[j][i] = fmaf(hv[3][i], w4.w, acc[j][i]);
      }
    }
  }
}

template <int TOC, int TN, int NTPO>
__device__ __forceinline__ void store_relu(float* hout,
                                           float (&acc)[TOC][TN], int tn) {
#pragma unroll
  for (int j = 0; j < TOC; ++j) {
    float* dst = &hout[j * NTPO + tn * TN];
    if constexpr (TN == 1) {
      dst[0] = fmaxf(acc[j][0], 0.0f);
    } else if constexpr (TN == 2) {
      *(float2*)dst = make_float2(fmaxf(acc[j][0], 0.0f),
                                  fmaxf(acc[j][1], 0.0f));
    } else {
      *(float4*)dst = make_float4(fmaxf(acc[j][0], 0.0f),
                                  fmaxf(acc[j][1], 0.0f),
                                  fmaxf(acc[j][2], 0.0f),
                                  fmaxf(acc[j][3], 0.0f));
    }
  }
}

template <int TOC, int TN>
__device__ __forceinline__ float rmax_dot(const float* wfp,
                                          float (&acc)[TOC][TN], int tn) {
  float s = 0.0f;
#pragma unroll
  for (int j = 0; j < TOC; ++j) {
    float v = 0.0f;
#pragma unroll
    for (int i = 0; i < TN; ++i) v = fmaxf(v, acc[j][i]);
    v = fmaxf(v, __shfl_xor(v, 1));
    v = fmaxf(v, __shfl_xor(v, 2));
    v = fmaxf(v, __shfl_xor(v, 4));
    v = fmaxf(v, __shfl_xor(v, 8));
    if (tn == 0) s = fmaf(v, wfp[j], s);
  }
  return s;
}

// ---------------------------------------------------------------------------
// Fused pipelined kernel. LDS = 6160 floats = 24640 B.
//   head @ 0..15: ticket@0, bc@4, wsum@8
//   h2p  @ 16: packed bf16 hi/lo [64 n][24 granules of 16B] = 24576 B.
//     granule g = kc*2 + (0=hi,1=lo), kc = k/8 (k<96); stored at g ^ (n&7).
//   transient aliases (dead before W6): masks @16..400 | gl @400..488 |
//     cbuf @488..760 | sB @760..2936 | sA @2936..5112
// W6/W8: fused L20+L21 wave scheme -> h2p (bf16 hi/lo split).
// W7/W9: L22 via dual-bf16 MFMA (Ah*Bh + Ah*Bl + Al*Bh).
// ---------------------------------------------------------------------------
__global__ __launch_bounds__(256) void fused_kernel(
    const float* __restrict__ pcd, float* __restrict__ new_xyz,
    int* __restrict__ ctrl, const float* __restrict__ wt,
    const unsigned short* __restrict__ aw,
    const float* __restrict__ b00, const float* __restrict__ b01,
    const float* __restrict__ b02, const float* __restrict__ b10,
    const float* __restrict__ b11, const float* __restrict__ b12,
    const float* __restrict__ b21, const float* __restrict__ b22,
    const float* __restrict__ wf, const float* __restrict__ bf,
    float* __restrict__ out) {
  __shared__ __align__(16) float lds[6160];   // 24640 B

  const int tid = threadIdx.x;
  int* progress = ctrl + 8;

  if (tid == 0) ((int*)lds)[0] = atomicAdd(&ctrl[0], 1);
  __syncthreads();
  const int ticket = ((int*)lds)[0];

  if (ticket < BATCH) {
    // ================= producer: FPS for batch = ticket =================
    const int b = ticket;
    const int t = tid;
    const int wave = t >> 6, lane = t & 63;
    const float* xb = pcd + (size_t)b * NPTS * 3;
    float4* slot = (float4*)(lds + 16);        // [2][4] parity dbuf

    float X[16], Y[16], Z[16], mind[16];
    {
      float f[48];
      float4* vv = (float4*)f;
      const float4* src = (const float4*)xb + t * 12;
#pragma unroll
      for (int q = 0; q < 12; ++q) vv[q] = src[q];
#pragma unroll
      for (int j = 0; j < 16; ++j) {
        X[j] = f[3 * j + 0]; Y[j] = f[3 * j + 1]; Z[j] = f[3 * j + 2];
        mind[j] = 10000000000.0f;
      }
    }
    float px = xb[0], py = xb[1], pz = xb[2];

    for (int it = 0; it < NSAMP; ++it) {
      if (t == 0) {
        int* dst = (int*)(new_xyz + ((size_t)b * NSAMP + it) * 3);
        atomicExch(&dst[0], __float_as_int(px));
        atomicExch(&dst[1], __float_as_int(py));
        atomicExch(&dst[2], __float_as_int(pz));
        if ((it & 7) == 7)
          __hip_atomic_store(&progress[b], it + 1, __ATOMIC_RELEASE,
                             __HIP_MEMORY_SCOPE_AGENT);
      }
      float bv = -1.0f, bx = 0.0f, by = 0.0f, bz = 0.0f;
#pragma unroll
      for (int j = 0; j < 16; ++j) {
        float dx = __fsub_rn(X[j], px);
        float dy = __fsub_rn(Y[j], py);
        float dz = __fsub_rn(Z[j], pz);
        float d = __fadd_rn(__fadd_rn(__fmul_rn(dx, dx), __fmul_rn(dy, dy)),
                            __fmul_rn(dz, dz));
        float m = fminf(mind[j], d);
        mind[j] = m;
        bool g = m > bv;
        bv = g ? m : bv;
        bx = g ? X[j] : bx; by = g ? Y[j] : by; bz = g ? Z[j] : bz;
      }
      float wmax = __int_as_float(
          __builtin_amdgcn_readlane(__float_as_int(wave_max(bv)), 63));
      unsigned long long msk = __ballot(bv == wmax);
      if (lane == __ffsll(msk) - 1)
        slot[(it & 1) * 4 + wave] = make_float4(bx, by, bz, wmax);
      __syncthreads();
      float4 cur = slot[(it & 1) * 4 + 0];
#pragma unroll
      for (int w = 1; w < 4; ++w) {
        float4 sw = slot[(it & 1) * 4 + w];
        if (sw.w > cur.w) cur = sw;
      }
      px = cur.x; py = cur.y; pz = cur.z;
    }
    return;
  }

  // ================= consumer: ball query + MLPs for one sample =========
  const int tk = ticket - BATCH;
  const int b = tk & 7;
  const int s = tk >> 3;
  const int bs = (b << 9) | s;
  const int lane = tid & 63;
  const int wave = tid >> 6;
  const int tn = tid & 15, toc = tid >> 4;
  const float* xb = pcd + (size_t)b * NPTS * 3;

  float* bc = lds + 4;
  float* wsum = lds + 8;
  char* h2b = (char*)(lds + 16);                          // packed bf16 h2
  unsigned long long* masks = (unsigned long long*)(lds + 16);   // 16..400
  unsigned short* gl = (unsigned short*)(lds + 400);      // 400..488
  float* cbuf = lds + 488;                                // 488..760
  float* sB = lds + 760;                                  // 760..2936
  float* sA = lds + 2936;                                 // 2936..5112

  if (tid == 0) {
    while (__hip_atomic_load(&progress[b], __ATOMIC_ACQUIRE,
                             __HIP_MEMORY_SCOPE_AGENT) <= s)
      __builtin_amdgcn_s_sleep(2);
    const int* src = (const int*)(new_xyz + (size_t)bs * 3);
    bc[0] = __int_as_float(__hip_atomic_load(&src[0], __ATOMIC_RELAXED,
                                             __HIP_MEMORY_SCOPE_AGENT));
    bc[1] = __int_as_float(__hip_atomic_load(&src[1], __ATOMIC_RELAXED,
                                             __HIP_MEMORY_SCOPE_AGENT));
    bc[2] = __int_as_float(__hip_atomic_load(&src[2], __ATOMIC_RELAXED,
                                             __HIP_MEMORY_SCOPE_AGENT));
  }
  __syncthreads();
  const float cx = bc[0], cy = bc[1], cz = bc[2];

  // ---- P1: in-radius bitmasks (3 radii x 64 chunks) ----
  const float r2a = (float)(0.1 * 0.1);
  const float r2b = (float)(0.2 * 0.2);
  const float r2c = (float)(0.4 * 0.4);
#pragma unroll 4
  for (int j = 0; j < 16; ++j) {
    int i = (j << 8) | tid;
    const float* p = xb + i * 3;
    float dx = __fsub_rn(cx, p[0]);
    float dy = __fsub_rn(cy, p[1]);
    float dz = __fsub_rn(cz, p[2]);
    float sq = __fadd_rn(__fadd_rn(__fmul_rn(dx, dx), __fmul_rn(dy, dy)),
                         __fmul_rn(dz, dz));
    unsigned long long m0 = __ballot(sq < r2a);
    unsigned long long m1 = __ballot(sq < r2b);
    unsigned long long m2 = __ballot(sq < r2c);
    if (lane == 0) {
      int c = (j << 2) | wave;
      masks[0 * 64 + c] = m0; masks[1 * 64 + c] = m1; masks[2 * 64 + c] = m2;
    }
  }
  __syncthreads();

  // ---- P2: wave s builds ordered padded list for scale s ----
  if (wave < 3) {
    const int ns  = (wave == 0) ? 16 : (wave == 1) ? 32 : 128;
    const int off = (wave == 0) ? 0  : (wave == 1) ? 16 : 48;
    unsigned long long m = masks[wave * 64 + lane];
    int pc = (int)__popcll(m);
    int incl = pc;
#pragma unroll
    for (int o = 1; o < 64; o <<= 1) {
      int u = __shfl_up(incl, o);
      if (lane >= o) incl += u;
    }
    int ex = incl - pc;
    int total = __shfl(incl, 63);
    unsigned short* glw = gl + off;
    unsigned long long mm = m;
    int p = ex;
    while (mm && p < ns) {
      int l = (int)__builtin_ctzll(mm);
      mm &= mm - 1;
      glw[p++] = (unsigned short)((lane << 6) | l);
    }
    int cnt = total < ns ? total : ns;
    unsigned long long nz = __ballot(pc > 0);
    int fl = __ffsll(nz) - 1;
    int myf = (lane << 6) | (int)__builtin_ctzll(m | 0x8000000000000000ull);
    int fidx = __shfl(myf, fl);
    for (int k = cnt + lane; k < ns; k += 64) glw[k] = (unsigned short)fidx;
  }
  __syncthreads();

  // W0: pad row + stage c0 (0-15) and c1 (16-47); scale-2 coords -> regs
  const int gi0 = gl[48 + lane];
  const int gi1 = gl[112 + lane];
  if (tid < 68) cbuf[3 * 68 + tid] = 0.0f;
  if (tid < 48) {
    int j = gl[tid];
    const float* p = xb + 3 * j;
    cbuf[0 * 68 + tid] = __fsub_rn(p[0], cx);
    cbuf[1 * 68 + tid] = __fsub_rn(p[1], cy);
    cbuf[2 * 68 + tid] = __fsub_rn(p[2], cz);
  }
  const float* q0 = xb + 3 * gi0;
  const float* q1 = xb + 3 * gi1;
  const float dx0 = __fsub_rn(q0[0], cx);
  const float dy0 = __fsub_rn(q0[1], cy);
  const float dz0 = __fsub_rn(q0[2], cz);
  const float dx1 = __fsub_rn(q1[0], cx);
  const float dy1 = __fsub_rn(q1[1], cy);
  const float dz1 = __fsub_rn(q1[2], cz);
  __syncthreads();

  const int wq = __builtin_amdgcn_readfirstlane(wave);
  float dot = 0.0f;

  // W1: L00  cbuf -> sB (stride 18)
  {
    float a[2][1]; ib<2, 1>(a, b00 + toc * 2);
    layer_acc<1, 2, 1, 68, 4>(wt + W00 + (toc * 2) * 4, cbuf, a, tn);
    store_relu<2, 1, 18>(sB + (toc * 2) * 18, a, tn);
  }
  __syncthreads();

  // W2: L01  sB -> sA (stride 18)
  {
    float a[2][1]; ib<2, 1>(a, b01 + toc * 2);
    layer_acc<8, 2, 1, 18, 32>(wt + W01 + (toc * 2) * 32, sB, a, tn);
    store_relu<2, 1, 18>(sA + (toc * 2) * 18, a, tn);
  }
  __syncthreads();

  // W3: L02 sA -> dot  ||  L10 cbuf+16 -> sB (stride 34)
  {
    float a[4][1]; ib<4, 1>(a, b02 + toc * 4);
    layer_acc<8, 4, 1, 18, 32>(wt + W02 + (toc * 4) * 32, sA, a, tn);
    dot += rmax_dot<4, 1>(wf + toc * 4, a, tn);
    float a1[4][2]; ib<4, 2>(a1, b10 + toc * 4);
    layer_acc<1, 4, 2, 68, 4>(wt + W10 + (toc * 4) * 4, cbuf + 16, a1, tn);
    store_relu<4, 2, 34>(sB + (toc * 4) * 34, a1, tn);
  }
  __syncthreads();

  // W4: L11 sB -> sA (stride 34)
  {
    float a[4][2]; ib<4, 2>(a, b11 + toc * 4);
    layer_acc<16, 4, 2, 34, 64>(wt + W11 + (toc * 4) * 64, sB, a, tn);
    store_relu<4, 2, 34>(sA + (toc * 4) * 34, a, tn);
  }
  __syncthreads();

  // W5: L12 sA -> dot (scale 1 done; aliases die here)
  {
    float a[8][2]; ib<8, 2>(a, b12 + toc * 8);
    layer_acc<16, 8, 2, 34, 64>(wt + W12 + (toc * 8) * 64, sA, a, tn);
    dot += rmax_dot<8, 2>(wf + 64 + toc * 8, a, tn);
  }
  __syncthreads();

  float rm2[8];
#pragma unroll
  for (int j = 0; j < 8; ++j) rm2[j] = 0.0f;
  const int fq = lane >> 4, fr = lane & 15;

#pragma unroll 1
  for (int pass = 0; pass < 2; ++pass) {
    const float pdx = pass ? dx1 : dx0;
    const float pdy = pass ? dy1 : dy0;
    const float pdz = pass ? dz1 : dz0;

    // W6/W8: fused L20+L21 -> h2p (bf16 hi/lo, swizzled granules)
    {
      const float* wp = wt + WROW + wq * 2048;   // [k][32]
      const float* bp = b21 + wq * 24;
      float acc[24];
#pragma unroll
      for (int j = 0; j < 24; ++j) acc[j] = bp[j];
#pragma unroll 4
      for (int k = 0; k < 64; ++k) {
        const float* row = wp + k * 32;
        float a2 = row[3];
        a2 = fmaf(pdx, row[0], a2);
        a2 = fmaf(pdy, row[1], a2);
        a2 = fmaf(pdz, row[2], a2);
        float hv = fmaxf(a2, 0.0f);
#pragma unroll
        for (int j = 0; j < 24; ++j) acc[j] = fmaf(hv, row[4 + j], acc[j]);
      }
      char* hb = h2b + lane * 384;
      const int nx = lane & 7;
#pragma unroll
      for (int c = 0; c < 3; ++c) {
        int ph[4], pl[4];
#pragma unroll
        for (int q = 0; q < 4; ++q) {
          float a0 = fmaxf(acc[c * 8 + 2 * q], 0.0f);
          float a1 = fmaxf(acc[c * 8 + 2 * q + 1], 0.0f);
          unsigned short h0 = f2bf(a0);
          unsigned short l0 = f2bf(__fsub_rn(a0, bf2f(h0)));
          unsigned short h1 = f2bf(a1);
          unsigned short l1 = f2bf(__fsub_rn(a1, bf2f(h1)));
          ph[q] = (int)((unsigned)h0 | ((unsigned)h1 << 16));
          pl[q] = (int)((unsigned)l0 | ((unsigned)l1 << 16));
        }
        const int g = 6 * wq + 2 * c;
        *(int4*)(hb + ((g ^ nx) << 4)) = make_int4(ph[0], ph[1], ph[2], ph[3]);
        *(int4*)(hb + (((g + 1) ^ nx) << 4)) =
            make_int4(pl[0], pl[1], pl[2], pl[3]);
      }
    }
    __syncthreads();

    // W7/W9: L22 via dual-bf16 MFMA. Wave wq owns oc-tiles {2wq, 2wq+1}.
    {
      f32x4 C[2][4];
#pragma unroll
      for (int i = 0; i < 2; ++i) {
        float bv[4];
#pragma unroll
        for (int r = 0; r < 4; ++r)
          bv[r] = b22[(wq * 2 + i) * 16 + fq * 4 + r];
#pragma unroll
        for (int t = 0; t < 4; ++t)
#pragma unroll
          for (int r = 0; r < 4; ++r) C[i][t][r] = bv[r];
      }
#pragma unroll
      for (int ks = 0; ks < 3; ++ks) {
        bf16x8 Ah[2], Al[2];
#pragma unroll
        for (int i = 0; i < 2; ++i) {
          const unsigned short* ab =
              aw + (((wq * 2 + i) * 3 + ks) * 64 + lane) * 16;
          Ah[i] = *(const bf16x8*)ab;
          Al[i] = *(const bf16x8*)(ab + 8);
        }
        const int kc = ks * 4 + fq;
#pragma unroll
        for (int t = 0; t < 4; ++t) {
          const int n = t * 16 + fr, nx = n & 7;
          const char* nb = h2b + n * 384;
          bf16x8 Bh = *(const bf16x8*)(nb + (((2 * kc) ^ nx) << 4));
          bf16x8 Bl = *(const bf16x8*)(nb + (((2 * kc + 1) ^ nx) << 4));
#pragma unroll
          for (int i = 0; i < 2; ++i) {
            C[i][t] = __builtin_amdgcn_mfma_f32_16x16x32_bf16(
                Ah[i], Bh, C[i][t], 0, 0, 0);
            C[i][t] = __builtin_amdgcn_mfma_f32_16x16x32_bf16(
                Ah[i], Bl, C[i][t], 0, 0, 0);
            C[i][t] = __builtin_amdgcn_mfma_f32_16x16x32_bf16(
                Al[i], Bh, C[i][t], 0, 0, 0);
          }
        }
      }
#pragma unroll
      for (int i = 0; i < 2; ++i)
#pragma unroll
        for (int t = 0; t < 4; ++t)
#pragma unroll
          for (int r = 0; r < 4; ++r)
            rm2[i * 4 + r] = fmaxf(rm2[i * 4 + r], fmaxf(C[i][t][r], 0.0f));
    }
    __syncthreads();
  }

  // pool-reduce over the 16 fr lanes; fr==0 lanes accumulate dot
#pragma unroll
  for (int i = 0; i < 2; ++i)
#pragma unroll
    for (int r = 0; r < 4; ++r) {
      float v = rm2[i * 4 + r];
      v = fmaxf(v, __shfl_xor(v, 1));
      v = fmaxf(v, __shfl_xor(v, 2));
      v = fmaxf(v, __shfl_xor(v, 4));
      v = fmaxf(v, __shfl_xor(v, 8));
      if (fr == 0)
        dot = fmaf(v, wf[192 + (wq * 2 + i) * 16 + fq * 4 + r], dot);
    }

  // W10: block sum of per-thread partial dots
#pragma unroll
  for (int o = 1; o < 64; o <<= 1) dot += __shfl_xor(dot, o);
  if (lane == 0) wsum[wq] = dot;
  __syncthreads();
  if (tid == 0)
    out[bs] = wsum[0] + wsum[1] + wsum[2] + wsum[3] + bf[0];
}

extern "C" void kernel_launch(void* const* d_in, const int* in_sizes, int n_in,
                              void* d_out, int out_size, void* d_ws, size_t ws_size,
                              hipStream_t stream) {
  const float* pcd = (const float*)d_in[0];
  float* wsf = (float*)d_ws;
  float* new_xyz = wsf;                               // 12288 floats
  float* wt = wsf + 12288;                            // 23936 floats (ids)
  unsigned short* aw = (unsigned short*)(wsf + 36224);  // 24576 u16
  int* ctrl = (int*)(wsf + 48512);                    // claim + progress

  hipMemsetAsync(ctrl, 0, 64, stream);

  prep_kernel<<<(ID_TOTAL + 255) / 256, 256, 0, stream>>>(
      (const float*)d_in[1], (const float*)d_in[3], (const float*)d_in[5],
      (const float*)d_in[7], (const float*)d_in[9], (const float*)d_in[11],
      (const float*)d_in[13], (const float*)d_in[14], (const float*)d_in[15],
      (const float*)d_in[17], wt, aw);

  fused_kernel<<<BATCH * NSAMP + BATCH, 256, 0, stream>>>(
      pcd, new_xyz, ctrl, wt, aw,
      (const float*)d_in[2],  (const float*)d_in[4],  (const float*)d_in[6],
      (const float*)d_in[8],  (const float*)d_in[10], (const float*)d_in[12],
      (const float*)d_in[16], (const float*)d_in[18],
      (const float*)d_in[19], (const float*)d_in[20],
      (float*)d_out);
}